// Round 5
// baseline (114.301 us; speedup 1.0000x reference)
//
#include <hip/hip_runtime.h>

#define WINDOW 48
#define RES 50
#define PRED 96
#define SEG 100
#define BATCH 2048
#define KTRUNC 12
#define XSTRIDE 52   // staged-x LDS row stride (floats): 16B-aligned rows
#define VSTRIDE 51   // Vt LDS row stride: odd -> conflict-free b32 both phases

// ws layout (floats):
//   M  [RES][WINDOW]  @ 0     (2400)
//   Dk [16][RES]      @ 2400  (800)
//   Wt [RES][PRED]    @ 3200  (4800)   (transposed W_out)
//   L  [BATCH][RES]   @ 8000  (102400)

__global__ __launch_bounds__(128) void k0_setup(const float* __restrict__ W_lin,
                                                const float* __restrict__ W_in,
                                                const float* __restrict__ d,
                                                const float* __restrict__ W_out,
                                                float* __restrict__ ws) {
    float* M  = ws;
    float* Dk = ws + 2400;
    float* Wt = ws + 3200;
    int f = blockIdx.x * 128 + threadIdx.x;
    if (f < 2400) {
        // M[r][w] = sum_v W_in[r][v] * W_lin[v][w]
        int r = f / WINDOW, w = f % WINDOW;
        float acc = 0.f;
        for (int v = 0; v < WINDOW; ++v)
            acc = fmaf(W_in[r * WINDOW + v], W_lin[v * WINDOW + w], acc);
        M[f] = acc;
    } else if (f < 7200) {
        int e = f - 2400;           // Wt[r][o] = W_out[o][r]
        int r = e / PRED, o = e % PRED;
        Wt[e] = W_out[o * RES + r];
    } else if (f < 7250) {
        int c = f - 7200;
        float dv = d[c];
        float d2 = dv * dv, d4 = d2 * d2, d8 = d4 * d4;
        float d16 = d8 * d8, d32 = d16 * d16, d64 = d32 * d32;
        float D = d64 * d32 * d4;   // d^100
        float p = 1.f;
        for (int k = 0; k < 16; ++k) { Dk[k * RES + c] = p; p *= D; }
    }
}

// One block (128 thr = 2 waves) per batch b.
//  1) stage x[b] (4800 f32) into LDS, fully coalesced float4.
//  2) lane j<100 pulls window j into 48 VGPRs (12x ds_read_b128, one-time).
//  3) c-loop: M row via software-pipelined loads (mn prefetched one full row
//     ahead of use -> ~96 cyc latency cover); 48 FMAs; dot -> Vt[j][c] in LDS.
//  4) lane r<50: exact Horner over j: L[b][r] = sum_j d^(99-j) v[j][r].
__global__ __launch_bounds__(128, 2) void k1_local(const float* __restrict__ x,
                                                   const float* __restrict__ Mg,
                                                   const float* __restrict__ d,
                                                   float* __restrict__ L) {
    __shared__ float S[SEG * XSTRIDE];   // 20.8 KB; phase A: Xs[100][52], phase B: Vt[100][51]
    int b = blockIdx.x;
    int t = threadIdx.x;

    // --- stage x row, coalesced ---
    const float4* xrow4 = (const float4*)(x + (size_t)b * (SEG * WINDOW));
#pragma unroll
    for (int i = 0; i < 10; ++i) {
        int e = i * 128 + t;
        if (e < 1200) {
            int j = e / 12, q = e % 12;
            *(float4*)(S + j * XSTRIDE + 4 * q) = xrow4[e];
        }
    }
    __syncthreads();

    // --- window into registers ---
    float4 xr[12];
    if (t < SEG) {
#pragma unroll
        for (int q = 0; q < 12; ++q)
            xr[q] = *(const float4*)(S + t * XSTRIDE + 4 * q);
    }
    __syncthreads();   // all x reads complete before S is reused as Vt

    if (t < SEG) {
        float4 mc[12], mn[12];
        const float4* m0 = (const float4*)Mg;
#pragma unroll
        for (int q = 0; q < 12; ++q) mc[q] = m0[q];

        for (int c = 0; c < RES; ++c) {
            int cn = (c < RES - 1) ? (c + 1) : c;
            const float4* mrow = (const float4*)(Mg + cn * WINDOW);
#pragma unroll
            for (int q = 0; q < 12; ++q) mn[q] = mrow[q];   // prefetch next row

            float ax = 0.f, ay = 0.f, az = 0.f, aw = 0.f;
#pragma unroll
            for (int q = 0; q < 12; ++q) {
                ax = fmaf(xr[q].x, mc[q].x, ax);
                ay = fmaf(xr[q].y, mc[q].y, ay);
                az = fmaf(xr[q].z, mc[q].z, az);
                aw = fmaf(xr[q].w, mc[q].w, aw);
            }
            S[t * VSTRIDE + c] = (ax + ay) + (az + aw);     // Vt[j][c]

#pragma unroll
            for (int q = 0; q < 12; ++q) mc[q] = mn[q];
        }
    }
    __syncthreads();

    if (t < RES) {
        float dv = d[t];
        float s = 0.f;
#pragma unroll 4
        for (int j = 0; j < SEG; ++j)
            s = fmaf(s, dv, S[j * VSTRIDE + t]);   // coalesced lanes, exact Horner
        L[b * RES + t] = s;
    }
}

// One block per batch: s[r] = sum_k Dk[k][r]*L[b-k][r]; out[b][o] = sum_r s[r]*Wt[r][o]
__global__ __launch_bounds__(128) void k2_out(const float* __restrict__ L,
                                              const float* __restrict__ Dk,
                                              const float* __restrict__ Wt,
                                              float* __restrict__ out) {
    __shared__ float s_s[52];
    int b = blockIdx.x;
    int t = threadIdx.x;
    if (t < RES) {
        float acc = 0.f;
#pragma unroll
        for (int k = 0; k < KTRUNC; ++k) {
            int bb = b - k;
            if (bb >= 0) acc = fmaf(Dk[k * RES + t], L[bb * RES + t], acc);
        }
        s_s[t] = acc;
    }
    __syncthreads();
    if (t < PRED) {
        float acc = 0.f;
#pragma unroll 10
        for (int r = 0; r < RES; ++r)
            acc = fmaf(s_s[r], Wt[r * PRED + t], acc);   // coalesced Wt reads
        out[b * PRED + t] = acc;
    }
}

extern "C" void kernel_launch(void* const* d_in, const int* in_sizes, int n_in,
                              void* d_out, int out_size, void* d_ws, size_t ws_size,
                              hipStream_t stream) {
    const float* x     = (const float*)d_in[0];
    const float* W_lin = (const float*)d_in[1];
    const float* W_in  = (const float*)d_in[2];
    const float* d     = (const float*)d_in[3];
    const float* W_out = (const float*)d_in[4];
    float* out = (float*)d_out;
    float* ws  = (float*)d_ws;

    float* M  = ws;
    float* Dk = ws + 2400;
    float* Wt = ws + 3200;
    float* L  = ws + 8000;

    k0_setup<<<57, 128, 0, stream>>>(W_lin, W_in, d, W_out, ws);
    k1_local<<<BATCH, 128, 0, stream>>>(x, M, d, L);
    k2_out<<<BATCH, 128, 0, stream>>>(L, Dk, Wt, out);
}

// Round 6
// 41.761 us; speedup vs baseline: 2.7370x; 2.7370x over previous
//
#include <hip/hip_runtime.h>

#define WINDOW 48
#define RES 50
#define PRED 96
#define SEG 100
#define BATCH 2048
#define KTRUNC 12
#define XSTR 52   // Xs row stride (floats), 16B-aligned
#define MSTR 52   // Ms row stride
#define PSTR 51   // partials stride (odd -> conflict-free b32)

// ws layout (floats):
//   M  [50][48]   @ 0      (2400)
//   Dk [16][50]   @ 2400   (800)
//   Wt [50][96]   @ 3200   (4800)
//   DP [25][50]   @ 8000   (1250)   DP[wt][c] = d_c^(96-4*wt)
//   L  [2048][50] @ 9280   (102400)

__global__ __launch_bounds__(128) void k0_setup(const float* __restrict__ W_lin,
                                                const float* __restrict__ W_in,
                                                const float* __restrict__ d,
                                                const float* __restrict__ W_out,
                                                float* __restrict__ ws) {
    float* M  = ws;
    float* Dk = ws + 2400;
    float* Wt = ws + 3200;
    float* DP = ws + 8000;
    int f = blockIdx.x * 128 + threadIdx.x;
    if (f < 2400) {
        int r = f / WINDOW, w = f % WINDOW;
        float acc = 0.f;
        for (int v = 0; v < WINDOW; ++v)
            acc = fmaf(W_in[r * WINDOW + v], W_lin[v * WINDOW + w], acc);
        M[f] = acc;
    } else if (f < 7200) {
        int e = f - 2400;               // Wt[r][o] = W_out[o][r]
        int r = e / PRED, o = e % PRED;
        Wt[e] = W_out[o * RES + r];
    } else if (f < 8450) {
        int e = f - 7200;               // DP[wt][c] = (d_c^4)^(24-wt)
        int wt = e / RES, c = e % RES;
        float dv = d[c];
        float d2 = dv * dv, d4 = d2 * d2;
        int ee = 24 - wt;
        float pw = 1.f, base = d4;
        while (ee) { if (ee & 1) pw *= base; base *= base; ee >>= 1; }
        DP[e] = pw;
    } else if (f < 8500) {
        int c = f - 8450;
        float dv = d[c];
        float d2 = dv * dv, d4 = d2 * d2, d8 = d4 * d4;
        float d16 = d8 * d8, d32 = d16 * d16, d64 = d32 * d32;
        float D = d64 * d32 * d4;       // d^100
        float p = 1.f;
        for (int k = 0; k < 16; ++k) { Dk[k * RES + c] = p; p *= D; }
    }
}

// One block (128 thr) per batch. Register-tiled GEMM:
// thread (wt=t/5 in 0..24, ct=t%5): 4 windows (4wt..4wt+3) x 10 channels (10ct..10ct+9),
// 40 accumulators; k in 12 chunks of 4 via b128 from LDS (x AND m), kc rotated by wt
// to break bank degeneracy. Then 4-term Horner * DP weight -> Ps, 25-way reduce -> L.
__global__ __launch_bounds__(128, 2) void k1_local(const float* __restrict__ x,
                                                   const float* __restrict__ ws,
                                                   const float* __restrict__ d,
                                                   float* __restrict__ L) {
    __shared__ float Xs[SEG * XSTR];   // 20.8 KB; aliased as Ps[25][51] after k-loop
    __shared__ float Ms[RES * MSTR];   // 10.4 KB
    const float* Mg = ws;
    const float* DP = ws + 8000;

    int b = blockIdx.x;
    int t = threadIdx.x;

    // --- stage x (coalesced float4) ---
    const float4* xr4 = (const float4*)(x + (size_t)b * (SEG * WINDOW));
#pragma unroll
    for (int i = 0; i < 10; ++i) {
        int e = i * 128 + t;
        if (e < 1200) {
            int j = e / 12, q = e % 12;
            *(float4*)(Xs + j * XSTR + 4 * q) = xr4[e];
        }
    }
    // --- stage M ---
    const float4* mr4 = (const float4*)Mg;
#pragma unroll
    for (int i = 0; i < 5; ++i) {
        int e = i * 128 + t;
        if (e < 600) {
            int r = e / 12, q = e % 12;
            *(float4*)(Ms + r * MSTR + 4 * q) = mr4[e];
        }
    }

    int wt = t / 5;          // 0..24 (window tile)
    int ct = t % 5;          // 0..4  (channel tile)
    int c0 = ct * 10;
    float dreg[10], dpreg[10];
    if (t < 125) {           // prefetch weights while staging is in flight
#pragma unroll
        for (int cc = 0; cc < 10; ++cc) dreg[cc] = d[c0 + cc];
#pragma unroll
        for (int cc = 0; cc < 10; ++cc) dpreg[cc] = DP[wt * RES + c0 + cc];
    }
    __syncthreads();

    float acc[4][10];
    if (t < 125) {
#pragma unroll
        for (int i = 0; i < 4; ++i)
#pragma unroll
            for (int cc = 0; cc < 10; ++cc) acc[i][cc] = 0.f;

        int wtm = wt; if (wtm >= 12) wtm -= 12; if (wtm >= 12) wtm -= 12;
        int jb = 4 * wt;

        for (int kc = 0; kc < 12; ++kc) {
            int kk = kc + wtm; if (kk >= 12) kk -= 12;   // per-thread k rotation
            int xo = 4 * kk;
            float4 xv0 = *(const float4*)(Xs + (jb + 0) * XSTR + xo);
            float4 xv1 = *(const float4*)(Xs + (jb + 1) * XSTR + xo);
            float4 xv2 = *(const float4*)(Xs + (jb + 2) * XSTR + xo);
            float4 xv3 = *(const float4*)(Xs + (jb + 3) * XSTR + xo);
#pragma unroll
            for (int cc = 0; cc < 10; ++cc) {
                float4 mv = *(const float4*)(Ms + (c0 + cc) * MSTR + xo);
                float a0 = acc[0][cc], a1 = acc[1][cc], a2 = acc[2][cc], a3 = acc[3][cc];
                a0 = fmaf(xv0.x, mv.x, a0); a0 = fmaf(xv0.y, mv.y, a0);
                a0 = fmaf(xv0.z, mv.z, a0); a0 = fmaf(xv0.w, mv.w, a0);
                a1 = fmaf(xv1.x, mv.x, a1); a1 = fmaf(xv1.y, mv.y, a1);
                a1 = fmaf(xv1.z, mv.z, a1); a1 = fmaf(xv1.w, mv.w, a1);
                a2 = fmaf(xv2.x, mv.x, a2); a2 = fmaf(xv2.y, mv.y, a2);
                a2 = fmaf(xv2.z, mv.z, a2); a2 = fmaf(xv2.w, mv.w, a2);
                a3 = fmaf(xv3.x, mv.x, a3); a3 = fmaf(xv3.y, mv.y, a3);
                a3 = fmaf(xv3.z, mv.z, a3); a3 = fmaf(xv3.w, mv.w, a3);
                acc[0][cc] = a0; acc[1][cc] = a1; acc[2][cc] = a2; acc[3][cc] = a3;
            }
        }
    }
    __syncthreads();          // all Xs reads done -> alias as partials
    float* Ps = Xs;
    if (t < 125) {
#pragma unroll
        for (int cc = 0; cc < 10; ++cc) {
            float dv = dreg[cc];
            // h = acc0*d^3 + acc1*d^2 + acc2*d + acc3 ; weight d^(96-4wt)
            float h = fmaf(fmaf(fmaf(acc[0][cc], dv, acc[1][cc]), dv, acc[2][cc]), dv, acc[3][cc]);
            Ps[wt * PSTR + c0 + cc] = h * dpreg[cc];
        }
    }
    __syncthreads();
    if (t < RES) {
        float s = 0.f;
#pragma unroll
        for (int q = 0; q < 25; ++q) s += Ps[q * PSTR + t];
        L[b * RES + t] = s;
    }
}

// One block per batch: s[r] = sum_k Dk[k][r]*L[b-k][r]; out[b][o] = sum_r s[r]*Wt[r][o]
__global__ __launch_bounds__(128) void k2_out(const float* __restrict__ L,
                                              const float* __restrict__ Dk,
                                              const float* __restrict__ Wt,
                                              float* __restrict__ out) {
    __shared__ float s_s[52];
    int b = blockIdx.x;
    int t = threadIdx.x;
    if (t < RES) {
        float acc = 0.f;
#pragma unroll
        for (int k = 0; k < KTRUNC; ++k) {
            int bb = b - k;
            if (bb >= 0) acc = fmaf(Dk[k * RES + t], L[bb * RES + t], acc);
        }
        s_s[t] = acc;
    }
    __syncthreads();
    if (t < PRED) {
        float acc = 0.f;
#pragma unroll 10
        for (int r = 0; r < RES; ++r)
            acc = fmaf(s_s[r], Wt[r * PRED + t], acc);
        out[b * PRED + t] = acc;
    }
}

extern "C" void kernel_launch(void* const* d_in, const int* in_sizes, int n_in,
                              void* d_out, int out_size, void* d_ws, size_t ws_size,
                              hipStream_t stream) {
    const float* x     = (const float*)d_in[0];
    const float* W_lin = (const float*)d_in[1];
    const float* W_in  = (const float*)d_in[2];
    const float* d     = (const float*)d_in[3];
    const float* W_out = (const float*)d_in[4];
    float* out = (float*)d_out;
    float* ws  = (float*)d_ws;

    float* Dk = ws + 2400;
    float* Wt = ws + 3200;
    float* L  = ws + 9280;

    k0_setup<<<67, 128, 0, stream>>>(W_lin, W_in, d, W_out, ws);
    k1_local<<<BATCH, 128, 0, stream>>>(x, ws, d, L);
    k2_out<<<BATCH, 128, 0, stream>>>(L, Dk, Wt, out);
}